// Round 20
// baseline (96.601 us; speedup 1.0000x reference)
//
#include <hip/hip_runtime.h>

#define NN 150000
#define NE 600000
#define IND 128
#define HID 64
#define KMAX 32            // CSR bucket stride; in-deg ~Poisson(4), P(>32) ~ 1e-19
#define BSHIFT 8
#define NBUCK 586          // ceil(NN / 256)
#define SUBCAP 224         // per-(bucket,xcd) edge cap; mean ~129, +8 sigma
#define PARTB 293          // partition blocks, 8 edges/thread (2 x int4)
#define TPB 2              // gemm1 tiles per block (sequential, NO reg double-buffer)
#define GEMM_BLK 1172      // ceil(2344 / TPB)
#define NOUT 120000

typedef short s16x8 __attribute__((ext_vector_type(8)));
typedef float f32x4 __attribute__((ext_vector_type(4)));

__device__ __forceinline__ unsigned f2bf(float f) {
    unsigned u = __float_as_uint(f);
    return (u + 0x7FFFu + ((u >> 16) & 1u)) >> 16;   // RNE
}

#define ACC4(v, dr) \
    a0 = fmaf(__uint_as_float((v).x << 16), dr, a0); \
    a1 = fmaf(__uint_as_float((v).x & 0xFFFF0000u), dr, a1); \
    a2 = fmaf(__uint_as_float((v).y << 16), dr, a2); \
    a3 = fmaf(__uint_as_float((v).y & 0xFFFF0000u), dr, a3);

// ---------------- zero gcnt ----------------
__global__ void k_zero(int* __restrict__ gcnt) {
    int t = blockIdx.x * 256 + threadIdx.x;
    if (t < NBUCK * 8) gcnt[t] = 0;
}

// ---------------- edge partition: 8 edges/thread, LDS histogram ----------------
__global__ __launch_bounds__(256) void k_part(
        const int* __restrict__ rowv, const int* __restrict__ colv,
        int* __restrict__ gcnt, int2* __restrict__ ebuf) {
    __shared__ int hist[NBUCK];
    __shared__ int bases[NBUCK];
    int tid = threadIdx.x;
    for (int i = tid; i < NBUCK; i += 256) hist[i] = 0;
    __syncthreads();
    int4 r4[2], c4[2];
    int bk[8], sl[8];
    bool val[2];
    #pragma unroll
    for (int h = 0; h < 2; ++h) {
        int t = blockIdx.x * 512 + h * 256 + tid;
        val[h] = (t < NE / 4);
        if (val[h]) {
            r4[h] = ((const int4*)rowv)[t];
            c4[h] = ((const int4*)colv)[t];
            bk[4*h+0] = c4[h].x >> BSHIFT; sl[4*h+0] = atomicAdd(&hist[bk[4*h+0]], 1);
            bk[4*h+1] = c4[h].y >> BSHIFT; sl[4*h+1] = atomicAdd(&hist[bk[4*h+1]], 1);
            bk[4*h+2] = c4[h].z >> BSHIFT; sl[4*h+2] = atomicAdd(&hist[bk[4*h+2]], 1);
            bk[4*h+3] = c4[h].w >> BSHIFT; sl[4*h+3] = atomicAdd(&hist[bk[4*h+3]], 1);
        }
    }
    __syncthreads();
    int xcd = blockIdx.x & 7;
    for (int i = tid; i < NBUCK; i += 256)
        bases[i] = hist[i] ? atomicAdd(&gcnt[i * 8 + xcd], hist[i]) : 0;
    __syncthreads();
    #pragma unroll
    for (int h = 0; h < 2; ++h) {
        if (val[h]) {
            #pragma unroll
            for (int e = 0; e < 4; ++e) {
                int c = (e == 0) ? c4[h].x : (e == 1) ? c4[h].y : (e == 2) ? c4[h].z : c4[h].w;
                int r = (e == 0) ? r4[h].x : (e == 1) ? r4[h].y : (e == 2) ? r4[h].z : r4[h].w;
                int p = bases[bk[4*h+e]] + sl[4*h+e];
                if (p < SUBCAP) ebuf[(bk[4*h+e] * 8 + xcd) * SUBCAP + p] = make_int2(c, r);
            }
        }
    }
}

// ---------------- hetero: bucket sort + gemm1, INTERLEAVED roles ----------------
// Role by blockIdx: b%3==0 -> sort (k=b/3, 586 blocks); else gemm (gblk=2*(b/3)+b%3-1,
// 1172 blocks). Interleaving co-locates both types on every CU so sort latency and
// gemm compute overlap (breadth-first dispatch of a role-ordered grid phase-separates).
// Sort: block owns 256 nodes exclusively; LDS cursors; writes degrees + dinvf.
// gemm1: 2 tiles of 64 nodes; W1 staged once (fp32->bf16, XOR-swizzled byte^=(row&7)<<4).
__global__ __launch_bounds__(256) void k_sort_gemm1(
        const float* __restrict__ obs, const float* __restrict__ W1,
        unsigned short* __restrict__ xs,
        const int* __restrict__ gcnt, const int2* __restrict__ ebuf,
        int* __restrict__ cursor, float* __restrict__ dinvf,
        int* __restrict__ csr_src) {
    __shared__ char smem[64 * IND * 2];         // gemm: 16KB W1 tile; sort: cursors
    int tid = threadIdx.x;
    int b = blockIdx.x;
    int third = b / 3, rem = b - third * 3;
    if (rem == 0) {
        int k = third;
        int lo = k << BSHIFT;
        int* cnt = (int*)smem;
        cnt[tid] = 0;
        int lens[8];
        #pragma unroll
        for (int x = 0; x < 8; ++x) {           // hoisted: 8 run lengths in flight
            int l = gcnt[k * 8 + x];
            lens[x] = l > SUBCAP ? SUBCAP : l;
        }
        __syncthreads();
        for (int x = 0; x < 8; ++x) {
            const int2* run = ebuf + (size_t)(k * 8 + x) * SUBCAP;
            for (int i = tid; i < lens[x]; i += 256) {
                int2 e = run[i];
                int s = atomicAdd(&cnt[e.x - lo], 1);       // LDS atomic
                if (s < KMAX) csr_src[e.x * KMAX + s] = e.y;
            }
        }
        __syncthreads();
        int n = lo + tid;
        if (n < NN) {
            cursor[n] = cnt[tid];
            dinvf[n] = rsqrtf((float)(cnt[tid] + 1));
        }
        return;
    }
    char* sB = smem;
    int gblk = third * 2 + rem - 1;             // 0..1171

    {   // stage W1 fp32 -> bf16 swizzled (64 rows x 32 float4), once per 2 tiles
        const float4* Wsrc = (const float4*)W1;
        for (int idx = tid; idx < 64 * 32; idx += 256) {
            int row = idx >> 5, c4i = idx & 31;
            float4 w = Wsrc[idx];
            uint2 p;
            p.x = f2bf(w.x) | (f2bf(w.y) << 16);
            p.y = f2bf(w.z) | (f2bf(w.w) << 16);
            int byte = row * (IND * 2) + c4i * 8;
            byte ^= (row & 7) << 4;
            *(uint2*)(sB + byte) = p;
        }
    }
    __syncthreads();

    int wave = tid >> 6, lane = tid & 63;
    int r16 = lane & 15, kg = lane >> 4;

    for (int t = 0; t < TPB; ++t) {
        int base = (gblk * TPB + t) * 64;
        int arow = base + 16 * wave + r16;
        if (arow >= NN) arow = NN - 1;          // clamp; writes are guarded
        const float4* Ap = (const float4*)(obs + (size_t)arow * IND) + kg * 2;

        float4 va[8];
        #pragma unroll
        for (int s = 0; s < 4; ++s) {
            va[2 * s]     = Ap[s * 8];
            va[2 * s + 1] = Ap[s * 8 + 1];
        }

        f32x4 acc[4];
        #pragma unroll
        for (int j = 0; j < 4; ++j) acc[j] = (f32x4){0.f, 0.f, 0.f, 0.f};

        #pragma unroll
        for (int s = 0; s < 4; ++s) {
            float4 v0 = va[2 * s], v1 = va[2 * s + 1];
            s16x8 a;
            a[0] = (short)f2bf(v0.x); a[1] = (short)f2bf(v0.y);
            a[2] = (short)f2bf(v0.z); a[3] = (short)f2bf(v0.w);
            a[4] = (short)f2bf(v1.x); a[5] = (short)f2bf(v1.y);
            a[6] = (short)f2bf(v1.z); a[7] = (short)f2bf(v1.w);
            int kb = (s * 32 + kg * 8) * 2;
            #pragma unroll
            for (int j = 0; j < 4; ++j) {
                int row = 16 * j + r16;
                int byte = row * (IND * 2) + kb;
                byte ^= (row & 7) << 4;
                s16x8 bfr = *(const s16x8*)(sB + byte);
                acc[j] = __builtin_amdgcn_mfma_f32_16x16x32_bf16(a, bfr, acc[j], 0, 0, 0);
            }
        }

        #pragma unroll
        for (int r = 0; r < 4; ++r) {
            int n = base + 16 * wave + kg * 4 + r;
            if (n >= NN) continue;
            #pragma unroll
            for (int j = 0; j < 4; ++j) {
                int c = 16 * j + r16;
                xs[(size_t)n * HID + c] = (unsigned short)f2bf(acc[j][r]);
            }
        }
    }
}

// ---------------- fused agg1 + gemm2 (branch-free batched gathers) ----------------
__global__ __launch_bounds__(256) void k_agg_gemm(
        const unsigned short* __restrict__ xs, const int* __restrict__ cursor,
        const float* __restrict__ dinvf, const int* __restrict__ csr_src,
        const float* __restrict__ bias, const float* __restrict__ W2,
        unsigned short* __restrict__ xs2) {
    __shared__ char smem[2 * 64 * HID * 2];
    char* sA = smem;
    char* sB = smem + 64 * HID * 2;
    int tid = threadIdx.x;
    int base = blockIdx.x * 64;

    {   // stage W2 fp32 -> bf16 swizzled (64 rows x 16 float4)
        const float4* Wsrc = (const float4*)W2;
        for (int idx = tid; idx < 64 * 16; idx += 256) {
            int row = idx >> 4, c4i = idx & 15;
            float4 w = Wsrc[idx];
            uint2 p;
            p.x = f2bf(w.x) | (f2bf(w.y) << 16);
            p.y = f2bf(w.z) | (f2bf(w.w) << 16);
            int byte = row * (HID * 2) + c4i * 8;
            byte ^= (row & 7) << 4;
            *(uint2*)(sB + byte) = p;
        }
    }

    int lane = tid & 63;
    int l16 = lane & 15, gbase = lane & 48;
    int grp = tid >> 4;
    const uint2* src = (const uint2*)xs;
    float4 bb = ((const float4*)bias)[l16];

    int degA[4], cntA[4], idxA[4];
    uint2 svA[4];
    float drA[4];
    #pragma unroll
    for (int s4 = 0; s4 < 4; ++s4) {
        int node = base + s4 * 16 + grp;
        bool ok = node < NN;
        int nc = ok ? node : NN - 1;
        int deg = cursor[nc];
        degA[s4] = deg;
        cntA[s4] = ok ? (deg < KMAX ? deg : KMAX) : 0;
        idxA[s4] = csr_src[nc * KMAX + l16];    // 64B/group: slots 0..15
        svA[s4]  = src[(size_t)nc * 16 + l16];  // self row
    }
    #pragma unroll
    for (int s4 = 0; s4 < 4; ++s4) {
        drA[s4] = (l16 < cntA[s4]) ? dinvf[idxA[s4]] : 0.0f;
    }

    #pragma unroll
    for (int s4 = 0; s4 < 4; ++s4) {
        int row = s4 * 16 + grp;
        int node = base + row;
        int cnt = cntA[s4];
        float dn = rsqrtf((float)(degA[s4] + 1));
        uint2 sv = svA[s4];
        float a0 = __uint_as_float(sv.x << 16) * dn;
        float a1 = __uint_as_float(sv.x & 0xFFFF0000u) * dn;
        float a2 = __uint_as_float(sv.y << 16) * dn;
        float a3 = __uint_as_float(sv.y & 0xFFFF0000u) * dn;
        uint2 v[8];
        #pragma unroll
        for (int j = 0; j < 8; ++j) {
            int r = __shfl(idxA[s4], gbase + j, 64);
            r = (j < cnt) ? r : 0;
            v[j] = src[(size_t)r * 16 + l16];
        }
        #pragma unroll
        for (int j = 0; j < 8; ++j) {
            float dr = __shfl(drA[s4], gbase + j, 64);  // 0 for invalid slots
            ACC4(v[j], dr)
        }
        if (cnt > 8) {
            int c16 = cnt < 16 ? cnt : 16;
            for (int j = 8; j < c16; ++j) {
                int r    = __shfl(idxA[s4], gbase + j, 64);
                float dr = __shfl(drA[s4], gbase + j, 64);
                uint2 vv = src[(size_t)r * 16 + l16];
                ACC4(vv, dr)
            }
            for (int j = 16; j < cnt; ++j) {    // ultra-rare
                int r = csr_src[node * KMAX + j];
                float dr = dinvf[r];
                uint2 vv = src[(size_t)r * 16 + l16];
                ACC4(vv, dr)
            }
        }
        float h0 = fmaxf(fmaf(dn, a0, bb.x), 0.f);
        float h1 = fmaxf(fmaf(dn, a1, bb.y), 0.f);
        float h2 = fmaxf(fmaf(dn, a2, bb.z), 0.f);
        float h3 = fmaxf(fmaf(dn, a3, bb.w), 0.f);
        uint2 o;
        o.x = f2bf(h0) | (f2bf(h1) << 16);
        o.y = f2bf(h2) | (f2bf(h3) << 16);
        if (node >= NN) { o.x = 0u; o.y = 0u; }
        int byte = row * (HID * 2) + l16 * 8;
        byte ^= (row & 7) << 4;
        *(uint2*)(sA + byte) = o;
    }
    __syncthreads();

    int wave = tid >> 6;
    int wr = wave >> 1, wc = wave & 1;
    int r16 = lane & 15, kg = lane >> 4;

    f32x4 acc[2][2];
    #pragma unroll
    for (int i = 0; i < 2; ++i)
        #pragma unroll
        for (int j = 0; j < 2; ++j)
            acc[i][j] = (f32x4){0.f, 0.f, 0.f, 0.f};

    #pragma unroll
    for (int s = 0; s < HID / 32; ++s) {
        int kb = (s * 32 + kg * 8) * 2;
        s16x8 a[2], bfr[2];
        #pragma unroll
        for (int i = 0; i < 2; ++i) {
            int row = 32 * wr + 16 * i + r16;
            int byte = row * (HID * 2) + kb;
            byte ^= (row & 7) << 4;
            a[i] = *(const s16x8*)(sA + byte);
        }
        #pragma unroll
        for (int j = 0; j < 2; ++j) {
            int row = 32 * wc + 16 * j + r16;
            int byte = row * (HID * 2) + kb;
            byte ^= (row & 7) << 4;
            bfr[j] = *(const s16x8*)(sB + byte);
        }
        #pragma unroll
        for (int i = 0; i < 2; ++i)
            #pragma unroll
            for (int j = 0; j < 2; ++j)
                acc[i][j] = __builtin_amdgcn_mfma_f32_16x16x32_bf16(a[i], bfr[j], acc[i][j], 0, 0, 0);
    }

    #pragma unroll
    for (int i = 0; i < 2; ++i) {
        #pragma unroll
        for (int r = 0; r < 4; ++r) {
            int n = base + 32 * wr + 16 * i + kg * 4 + r;
            if (n >= NN) continue;
            float d = dinvf[n];                 // pre-scale layer-2 source side
            #pragma unroll
            for (int j = 0; j < 2; ++j) {
                int c = 32 * wc + 16 * j + r16;
                xs2[(size_t)n * HID + c] = (unsigned short)f2bf(acc[i][j][r] * d);
            }
        }
    }
}

// ---------------- agg2 + final dot (needed nodes only; batched gathers) ----------------
__global__ __launch_bounds__(256) void k_agg_out(const unsigned short* __restrict__ xs,
                      const int* __restrict__ cursor, const int* __restrict__ csr_src,
                      const float* __restrict__ bias, const float* __restrict__ W3,
                      const float* __restrict__ b3, float* __restrict__ outp) {
    int tid = threadIdx.x;
    int lane = tid & 63;
    int l16 = lane & 15, gbase = lane & 48;
    int q = blockIdx.x * 16 + (tid >> 4);
    if (q >= NOUT) return;
    int g15 = q / 12, jj12 = q - g15 * 12;
    int node = g15 * 15 + 3 + jj12;
    int deg = cursor[node];
    int cnt = deg < KMAX ? deg : KMAX;
    float dn = rsqrtf((float)(deg + 1));
    const uint2* src = (const uint2*)xs;
    int idx0 = csr_src[node * KMAX + l16];      // 64B: slots 0..15
    float w0 = (l16 < cnt) ? 1.0f : 0.0f;       // slot validity weight
    uint2 sv = src[(size_t)node * 16 + l16];
    float a0 = __uint_as_float(sv.x << 16);
    float a1 = __uint_as_float(sv.x & 0xFFFF0000u);
    float a2 = __uint_as_float(sv.y << 16);
    float a3 = __uint_as_float(sv.y & 0xFFFF0000u);
    uint2 v[8];
    #pragma unroll
    for (int j = 0; j < 8; ++j) {
        int r = __shfl(idx0, gbase + j, 64);
        r = (j < cnt) ? r : 0;
        v[j] = src[(size_t)r * 16 + l16];
    }
    #pragma unroll
    for (int j = 0; j < 8; ++j) {
        float w = __shfl(w0, gbase + j, 64);
        ACC4(v[j], w)
    }
    if (cnt > 8) {
        int c16 = cnt < 16 ? cnt : 16;
        for (int j = 8; j < c16; ++j) {
            int r = __shfl(idx0, gbase + j, 64);
            uint2 vv = src[(size_t)r * 16 + l16];
            ACC4(vv, 1.0f)
        }
        for (int j = 16; j < cnt; ++j) {
            int r = csr_src[node * KMAX + j];
            uint2 vv = src[(size_t)r * 16 + l16];
            ACC4(vv, 1.0f)
        }
    }
    float4 bb = ((const float4*)bias)[l16];
    float h0 = fmaxf(fmaf(dn, a0, bb.x), 0.f);
    float h1 = fmaxf(fmaf(dn, a1, bb.y), 0.f);
    float h2 = fmaxf(fmaf(dn, a2, bb.z), 0.f);
    float h3 = fmaxf(fmaf(dn, a3, bb.w), 0.f);
    float4 ww = ((const float4*)W3)[l16];
    float v3 = h0 * ww.x + h1 * ww.y + h2 * ww.z + h3 * ww.w;
    v3 += __shfl_xor(v3, 1, 64);
    v3 += __shfl_xor(v3, 2, 64);
    v3 += __shfl_xor(v3, 4, 64);
    v3 += __shfl_xor(v3, 8, 64);                // reduce within the 16-lane group
    if (l16 == 0) outp[q] = v3 + b3[0];
}

extern "C" void kernel_launch(void* const* d_in, const int* in_sizes, int n_in,
                              void* d_out, int out_size, void* d_ws, size_t ws_size,
                              hipStream_t stream) {
    const float* obs = (const float*)d_in[0];
    const int*   ei  = (const int*)d_in[1];
    const float* W1  = (const float*)d_in[2];
    const float* b1  = (const float*)d_in[3];
    const float* W2  = (const float*)d_in[4];
    const float* b2  = (const float*)d_in[5];
    const float* W3  = (const float*)d_in[6];
    const float* b3  = (const float*)d_in[7];
    float* out = (float*)d_out;

    char* ws = (char*)d_ws;
    size_t off = 0;
    auto alloc = [&](size_t bytes) -> void* {
        void* p = ws + off;
        off += (bytes + 255) & ~(size_t)255;
        return p;
    };
    int*   gcnt    = (int*)  alloc((size_t)NBUCK * 8 * 4);          // 18.8 KB
    int*   cursor  = (int*)  alloc((size_t)NN * 4);
    float* dinvf   = (float*)alloc((size_t)NN * 4);
    int*   csr_src = (int*)  alloc((size_t)NN * KMAX * 4);          // 19.2 MB
    int2*  ebuf    = (int2*) alloc((size_t)NBUCK * 8 * SUBCAP * 8); // 8.4 MB
    unsigned short* XB  = (unsigned short*)alloc((size_t)NN * HID * 2);
    unsigned short* XB2 = (unsigned short*)alloc((size_t)NN * HID * 2);

    const int* rowv = ei;
    const int* colv = ei + NE;

    k_zero<<<(NBUCK * 8 + 255) / 256, 256, 0, stream>>>(gcnt);
    k_part<<<PARTB, 256, 0, stream>>>(rowv, colv, gcnt, ebuf);
    k_sort_gemm1<<<NBUCK + GEMM_BLK, 256, 0, stream>>>(obs, W1, XB, gcnt, ebuf,
                                                       cursor, dinvf, csr_src);
    k_agg_gemm<<<(NN + 63) / 64, 256, 0, stream>>>(XB, cursor, dinvf, csr_src, b1, W2, XB2);
    k_agg_out<<<(NOUT + 15) / 16, 256, 0, stream>>>(XB2, cursor, csr_src, b2, W3, b3, out);
}

// Round 21
// 93.359 us; speedup vs baseline: 1.0347x; 1.0347x over previous
//
#include <hip/hip_runtime.h>

#define NN 150000
#define NE 600000
#define IND 128
#define HID 64
#define KMAX 32            // CSR bucket stride; in-deg ~Poisson(4), P(>32) ~ 1e-19
#define BSHIFT 8
#define NBUCK 586          // ceil(NN / 256)
#define SUBCAP 224         // per-(bucket,xcd) edge cap; mean ~129, +8 sigma
#define PARTB 293          // partition blocks, 8 edges/thread (2 x int4)
#define GEMM_GRID ((NN + 63) / 64)       // 2344
#define NOUT 120000

typedef short s16x8 __attribute__((ext_vector_type(8)));
typedef float f32x4 __attribute__((ext_vector_type(4)));

__device__ __forceinline__ unsigned f2bf(float f) {
    unsigned u = __float_as_uint(f);
    return (u + 0x7FFFu + ((u >> 16) & 1u)) >> 16;   // RNE
}

#define ACC4(v, dr) \
    a0 = fmaf(__uint_as_float((v).x << 16), dr, a0); \
    a1 = fmaf(__uint_as_float((v).x & 0xFFFF0000u), dr, a1); \
    a2 = fmaf(__uint_as_float((v).y << 16), dr, a2); \
    a3 = fmaf(__uint_as_float((v).y & 0xFFFF0000u), dr, a3);

// ---------------- zero gcnt ----------------
__global__ void k_zero(int* __restrict__ gcnt) {
    int t = blockIdx.x * 256 + threadIdx.x;
    if (t < NBUCK * 8) gcnt[t] = 0;
}

// ---------------- edge partition: 8 edges/thread, LDS histogram ----------------
__global__ __launch_bounds__(256) void k_part(
        const int* __restrict__ rowv, const int* __restrict__ colv,
        int* __restrict__ gcnt, int2* __restrict__ ebuf) {
    __shared__ int hist[NBUCK];
    __shared__ int bases[NBUCK];
    int tid = threadIdx.x;
    for (int i = tid; i < NBUCK; i += 256) hist[i] = 0;
    __syncthreads();
    int4 r4[2], c4[2];
    int bk[8], sl[8];
    bool val[2];
    #pragma unroll
    for (int h = 0; h < 2; ++h) {
        int t = blockIdx.x * 512 + h * 256 + tid;
        val[h] = (t < NE / 4);
        if (val[h]) {
            r4[h] = ((const int4*)rowv)[t];
            c4[h] = ((const int4*)colv)[t];
            bk[4*h+0] = c4[h].x >> BSHIFT; sl[4*h+0] = atomicAdd(&hist[bk[4*h+0]], 1);
            bk[4*h+1] = c4[h].y >> BSHIFT; sl[4*h+1] = atomicAdd(&hist[bk[4*h+1]], 1);
            bk[4*h+2] = c4[h].z >> BSHIFT; sl[4*h+2] = atomicAdd(&hist[bk[4*h+2]], 1);
            bk[4*h+3] = c4[h].w >> BSHIFT; sl[4*h+3] = atomicAdd(&hist[bk[4*h+3]], 1);
        }
    }
    __syncthreads();
    int xcd = blockIdx.x & 7;
    for (int i = tid; i < NBUCK; i += 256)
        bases[i] = hist[i] ? atomicAdd(&gcnt[i * 8 + xcd], hist[i]) : 0;
    __syncthreads();
    #pragma unroll
    for (int h = 0; h < 2; ++h) {
        if (val[h]) {
            #pragma unroll
            for (int e = 0; e < 4; ++e) {
                int c = (e == 0) ? c4[h].x : (e == 1) ? c4[h].y : (e == 2) ? c4[h].z : c4[h].w;
                int r = (e == 0) ? r4[h].x : (e == 1) ? r4[h].y : (e == 2) ? r4[h].z : r4[h].w;
                int p = bases[bk[4*h+e]] + sl[4*h+e];
                if (p < SUBCAP) ebuf[(bk[4*h+e] * 8 + xcd) * SUBCAP + p] = make_int2(c, r);
            }
        }
    }
}

// ---------------- hetero: bucket sort (LDS cursors) + gemm1 (LDS-staged A) ----------------
// Sort blocks (first NBUCK): block k owns nodes [k*256, k*256+256) exclusively;
// LDS cursors; writes degrees + dinvf. gemm1 blocks: A-tile staged via LDS with
// FULLY LINEAR global reads (addr = base*32 + idx -> 1KB/wave-instr), fp32->bf16
// in-flight, XOR-swizzled (byte ^= (row&7)<<4); W1 likewise; C written through
// LDS (dead A-tile) and flushed as coalesced 16B stores.
__global__ __launch_bounds__(256) void k_sort_gemm1(
        const float* __restrict__ obs, const float* __restrict__ W1,
        unsigned short* __restrict__ xs,
        const int* __restrict__ gcnt, const int2* __restrict__ ebuf,
        int* __restrict__ cursor, float* __restrict__ dinvf,
        int* __restrict__ csr_src) {
    __shared__ char smem[2 * 64 * IND * 2];     // 32 KB: sA + sW (sort uses 1 KB)
    int tid = threadIdx.x;
    if (blockIdx.x < NBUCK) {
        int k = blockIdx.x;
        int lo = k << BSHIFT;
        int* cnt = (int*)smem;
        cnt[tid] = 0;
        int lens[8];
        #pragma unroll
        for (int x = 0; x < 8; ++x) {
            int l = gcnt[k * 8 + x];
            lens[x] = l > SUBCAP ? SUBCAP : l;
        }
        __syncthreads();
        for (int x = 0; x < 8; ++x) {
            const int2* run = ebuf + (size_t)(k * 8 + x) * SUBCAP;
            for (int i = tid; i < lens[x]; i += 256) {
                int2 e = run[i];
                int s = atomicAdd(&cnt[e.x - lo], 1);       // LDS atomic
                if (s < KMAX) csr_src[e.x * KMAX + s] = e.y;
            }
        }
        __syncthreads();
        int n = lo + tid;
        if (n < NN) {
            cursor[n] = cnt[tid];
            dinvf[n] = rsqrtf((float)(cnt[tid] + 1));
        }
        return;
    }
    char* sA = smem;
    char* sW = smem + 64 * IND * 2;
    int base = (blockIdx.x - NBUCK) * 64;

    {   // stage W1 fp32 -> bf16 swizzled (64 rows x 32 float4)
        const float4* Wsrc = (const float4*)W1;
        for (int idx = tid; idx < 64 * 32; idx += 256) {
            int row = idx >> 5, c4i = idx & 31;
            float4 w = Wsrc[idx];
            uint2 p;
            p.x = f2bf(w.x) | (f2bf(w.y) << 16);
            p.y = f2bf(w.z) | (f2bf(w.w) << 16);
            int byte = row * (IND * 2) + c4i * 8;
            byte ^= (row & 7) << 4;
            *(uint2*)(sW + byte) = p;
        }
    }
    {   // stage A tile: LINEAR addresses (n*32 + c4i == base*32 + idx when unclamped)
        const float4* Xsrc = (const float4*)obs;
        for (int idx = tid; idx < 64 * 32; idx += 256) {
            int row = idx >> 5, c4i = idx & 31;
            int n = base + row; if (n >= NN) n = NN - 1;
            float4 v = Xsrc[(size_t)n * 32 + c4i];
            uint2 p;
            p.x = f2bf(v.x) | (f2bf(v.y) << 16);
            p.y = f2bf(v.z) | (f2bf(v.w) << 16);
            int byte = row * (IND * 2) + c4i * 8;
            byte ^= (row & 7) << 4;
            *(uint2*)(sA + byte) = p;
        }
    }
    __syncthreads();

    int wave = tid >> 6, lane = tid & 63;
    int wr = wave >> 1, wc = wave & 1;
    int r16 = lane & 15, kg = lane >> 4;

    f32x4 acc[2][2];
    #pragma unroll
    for (int i = 0; i < 2; ++i)
        #pragma unroll
        for (int j = 0; j < 2; ++j)
            acc[i][j] = (f32x4){0.f, 0.f, 0.f, 0.f};

    #pragma unroll
    for (int s = 0; s < IND / 32; ++s) {
        int kb = (s * 32 + kg * 8) * 2;
        s16x8 a[2], b[2];
        #pragma unroll
        for (int i = 0; i < 2; ++i) {
            int row = 32 * wr + 16 * i + r16;
            int byte = row * (IND * 2) + kb;
            byte ^= (row & 7) << 4;
            a[i] = *(const s16x8*)(sA + byte);
        }
        #pragma unroll
        for (int j = 0; j < 2; ++j) {
            int row = 32 * wc + 16 * j + r16;
            int byte = row * (IND * 2) + kb;
            byte ^= (row & 7) << 4;
            b[j] = *(const s16x8*)(sW + byte);
        }
        #pragma unroll
        for (int i = 0; i < 2; ++i)
            #pragma unroll
            for (int j = 0; j < 2; ++j)
                acc[i][j] = __builtin_amdgcn_mfma_f32_16x16x32_bf16(a[i], b[j], acc[i][j], 0, 0, 0);
    }

    // C via LDS bounce (sA is dead after MFMA) -> coalesced 16B flush
    __syncthreads();
    unsigned short* sC = (unsigned short*)sA;
    #pragma unroll
    for (int i = 0; i < 2; ++i) {
        #pragma unroll
        for (int r = 0; r < 4; ++r) {
            int nloc = 32 * wr + 16 * i + kg * 4 + r;
            #pragma unroll
            for (int j = 0; j < 2; ++j) {
                int c = 32 * wc + 16 * j + r16;
                sC[nloc * 64 + c] = (unsigned short)f2bf(acc[i][j][r]);
            }
        }
    }
    __syncthreads();
    {
        uint4* dst = (uint4*)(xs + (size_t)base * HID);
        const uint4* s4p = (const uint4*)sC;
        #pragma unroll
        for (int k2 = 0; k2 < 2; ++k2) {
            int idx = k2 * 256 + tid;           // 8 uint4 per node row
            if (base + (idx >> 3) < NN) dst[idx] = s4p[idx];
        }
    }
}

// ---------------- fused agg1 + gemm2 (branch-free gathers; C via LDS flush) ----------------
__global__ __launch_bounds__(256) void k_agg_gemm(
        const unsigned short* __restrict__ xs, const int* __restrict__ cursor,
        const float* __restrict__ dinvf, const int* __restrict__ csr_src,
        const float* __restrict__ bias, const float* __restrict__ W2,
        unsigned short* __restrict__ xs2) {
    __shared__ char smem[2 * 64 * HID * 2];
    char* sA = smem;
    char* sB = smem + 64 * HID * 2;
    int tid = threadIdx.x;
    int base = blockIdx.x * 64;

    {   // stage W2 fp32 -> bf16 swizzled (64 rows x 16 float4)
        const float4* Wsrc = (const float4*)W2;
        for (int idx = tid; idx < 64 * 16; idx += 256) {
            int row = idx >> 4, c4i = idx & 15;
            float4 w = Wsrc[idx];
            uint2 p;
            p.x = f2bf(w.x) | (f2bf(w.y) << 16);
            p.y = f2bf(w.z) | (f2bf(w.w) << 16);
            int byte = row * (HID * 2) + c4i * 8;
            byte ^= (row & 7) << 4;
            *(uint2*)(sB + byte) = p;
        }
    }

    int lane = tid & 63;
    int l16 = lane & 15, gbase = lane & 48;
    int grp = tid >> 4;
    const uint2* src = (const uint2*)xs;
    float4 bb = ((const float4*)bias)[l16];

    int degA[4], cntA[4], idxA[4];
    uint2 svA[4];
    float drA[4];
    #pragma unroll
    for (int s4 = 0; s4 < 4; ++s4) {
        int node = base + s4 * 16 + grp;
        bool ok = node < NN;
        int nc = ok ? node : NN - 1;
        int deg = cursor[nc];
        degA[s4] = deg;
        cntA[s4] = ok ? (deg < KMAX ? deg : KMAX) : 0;
        idxA[s4] = csr_src[nc * KMAX + l16];    // 64B/group: slots 0..15
        svA[s4]  = src[(size_t)nc * 16 + l16];  // self row
    }
    #pragma unroll
    for (int s4 = 0; s4 < 4; ++s4) {
        drA[s4] = (l16 < cntA[s4]) ? dinvf[idxA[s4]] : 0.0f;
    }

    #pragma unroll
    for (int s4 = 0; s4 < 4; ++s4) {
        int row = s4 * 16 + grp;
        int node = base + row;
        int cnt = cntA[s4];
        float dn = rsqrtf((float)(degA[s4] + 1));
        uint2 sv = svA[s4];
        float a0 = __uint_as_float(sv.x << 16) * dn;
        float a1 = __uint_as_float(sv.x & 0xFFFF0000u) * dn;
        float a2 = __uint_as_float(sv.y << 16) * dn;
        float a3 = __uint_as_float(sv.y & 0xFFFF0000u) * dn;
        uint2 v[8];
        #pragma unroll
        for (int j = 0; j < 8; ++j) {
            int r = __shfl(idxA[s4], gbase + j, 64);
            r = (j < cnt) ? r : 0;
            v[j] = src[(size_t)r * 16 + l16];
        }
        #pragma unroll
        for (int j = 0; j < 8; ++j) {
            float dr = __shfl(drA[s4], gbase + j, 64);  // 0 for invalid slots
            ACC4(v[j], dr)
        }
        if (cnt > 8) {
            int c16 = cnt < 16 ? cnt : 16;
            for (int j = 8; j < c16; ++j) {
                int r    = __shfl(idxA[s4], gbase + j, 64);
                float dr = __shfl(drA[s4], gbase + j, 64);
                uint2 vv = src[(size_t)r * 16 + l16];
                ACC4(vv, dr)
            }
            for (int j = 16; j < cnt; ++j) {    // ultra-rare
                int r = csr_src[node * KMAX + j];
                float dr = dinvf[r];
                uint2 vv = src[(size_t)r * 16 + l16];
                ACC4(vv, dr)
            }
        }
        float h0 = fmaxf(fmaf(dn, a0, bb.x), 0.f);
        float h1 = fmaxf(fmaf(dn, a1, bb.y), 0.f);
        float h2 = fmaxf(fmaf(dn, a2, bb.z), 0.f);
        float h3 = fmaxf(fmaf(dn, a3, bb.w), 0.f);
        uint2 o;
        o.x = f2bf(h0) | (f2bf(h1) << 16);
        o.y = f2bf(h2) | (f2bf(h3) << 16);
        if (node >= NN) { o.x = 0u; o.y = 0u; }
        int byte = row * (HID * 2) + l16 * 8;
        byte ^= (row & 7) << 4;
        *(uint2*)(sA + byte) = o;
    }
    __syncthreads();

    int wave = tid >> 6;
    int wr = wave >> 1, wc = wave & 1;
    int r16 = lane & 15, kg = lane >> 4;

    f32x4 acc[2][2];
    #pragma unroll
    for (int i = 0; i < 2; ++i)
        #pragma unroll
        for (int j = 0; j < 2; ++j)
            acc[i][j] = (f32x4){0.f, 0.f, 0.f, 0.f};

    #pragma unroll
    for (int s = 0; s < HID / 32; ++s) {
        int kb = (s * 32 + kg * 8) * 2;
        s16x8 a[2], bfr[2];
        #pragma unroll
        for (int i = 0; i < 2; ++i) {
            int row = 32 * wr + 16 * i + r16;
            int byte = row * (HID * 2) + kb;
            byte ^= (row & 7) << 4;
            a[i] = *(const s16x8*)(sA + byte);
        }
        #pragma unroll
        for (int j = 0; j < 2; ++j) {
            int row = 32 * wc + 16 * j + r16;
            int byte = row * (HID * 2) + kb;
            byte ^= (row & 7) << 4;
            bfr[j] = *(const s16x8*)(sB + byte);
        }
        #pragma unroll
        for (int i = 0; i < 2; ++i)
            #pragma unroll
            for (int j = 0; j < 2; ++j)
                acc[i][j] = __builtin_amdgcn_mfma_f32_16x16x32_bf16(a[i], bfr[j], acc[i][j], 0, 0, 0);
    }

    // C via LDS bounce (sA dead) -> coalesced flush, pre-scaled by dinvf[n]
    __syncthreads();
    unsigned short* sC = (unsigned short*)sA;
    #pragma unroll
    for (int i = 0; i < 2; ++i) {
        #pragma unroll
        for (int r = 0; r < 4; ++r) {
            int nloc = 32 * wr + 16 * i + kg * 4 + r;
            int n = base + nloc;
            float d = dinvf[n < NN ? n : NN - 1];
            #pragma unroll
            for (int j = 0; j < 2; ++j) {
                int c = 32 * wc + 16 * j + r16;
                sC[nloc * 64 + c] = (unsigned short)f2bf(acc[i][j][r] * d);
            }
        }
    }
    __syncthreads();
    {
        uint4* dst = (uint4*)(xs2 + (size_t)base * HID);
        const uint4* s4p = (const uint4*)sC;
        #pragma unroll
        for (int k2 = 0; k2 < 2; ++k2) {
            int idx = k2 * 256 + tid;
            if (base + (idx >> 3) < NN) dst[idx] = s4p[idx];
        }
    }
}

// ---------------- agg2 + final dot (needed nodes only; batched gathers) ----------------
__global__ __launch_bounds__(256) void k_agg_out(const unsigned short* __restrict__ xs,
                      const int* __restrict__ cursor, const int* __restrict__ csr_src,
                      const float* __restrict__ bias, const float* __restrict__ W3,
                      const float* __restrict__ b3, float* __restrict__ outp) {
    int tid = threadIdx.x;
    int lane = tid & 63;
    int l16 = lane & 15, gbase = lane & 48;
    int q = blockIdx.x * 16 + (tid >> 4);
    if (q >= NOUT) return;
    int g15 = q / 12, jj12 = q - g15 * 12;
    int node = g15 * 15 + 3 + jj12;
    int deg = cursor[node];
    int cnt = deg < KMAX ? deg : KMAX;
    float dn = rsqrtf((float)(deg + 1));
    const uint2* src = (const uint2*)xs;
    int idx0 = csr_src[node * KMAX + l16];      // 64B: slots 0..15
    float w0 = (l16 < cnt) ? 1.0f : 0.0f;       // slot validity weight
    uint2 sv = src[(size_t)node * 16 + l16];
    float a0 = __uint_as_float(sv.x << 16);
    float a1 = __uint_as_float(sv.x & 0xFFFF0000u);
    float a2 = __uint_as_float(sv.y << 16);
    float a3 = __uint_as_float(sv.y & 0xFFFF0000u);
    uint2 v[8];
    #pragma unroll
    for (int j = 0; j < 8; ++j) {
        int r = __shfl(idx0, gbase + j, 64);
        r = (j < cnt) ? r : 0;
        v[j] = src[(size_t)r * 16 + l16];
    }
    #pragma unroll
    for (int j = 0; j < 8; ++j) {
        float w = __shfl(w0, gbase + j, 64);
        ACC4(v[j], w)
    }
    if (cnt > 8) {
        int c16 = cnt < 16 ? cnt : 16;
        for (int j = 8; j < c16; ++j) {
            int r = __shfl(idx0, gbase + j, 64);
            uint2 vv = src[(size_t)r * 16 + l16];
            ACC4(vv, 1.0f)
        }
        for (int j = 16; j < cnt; ++j) {
            int r = csr_src[node * KMAX + j];
            uint2 vv = src[(size_t)r * 16 + l16];
            ACC4(vv, 1.0f)
        }
    }
    float4 bb = ((const float4*)bias)[l16];
    float h0 = fmaxf(fmaf(dn, a0, bb.x), 0.f);
    float h1 = fmaxf(fmaf(dn, a1, bb.y), 0.f);
    float h2 = fmaxf(fmaf(dn, a2, bb.z), 0.f);
    float h3 = fmaxf(fmaf(dn, a3, bb.w), 0.f);
    float4 ww = ((const float4*)W3)[l16];
    float v3 = h0 * ww.x + h1 * ww.y + h2 * ww.z + h3 * ww.w;
    v3 += __shfl_xor(v3, 1, 64);
    v3 += __shfl_xor(v3, 2, 64);
    v3 += __shfl_xor(v3, 4, 64);
    v3 += __shfl_xor(v3, 8, 64);                // reduce within the 16-lane group
    if (l16 == 0) outp[q] = v3 + b3[0];
}

extern "C" void kernel_launch(void* const* d_in, const int* in_sizes, int n_in,
                              void* d_out, int out_size, void* d_ws, size_t ws_size,
                              hipStream_t stream) {
    const float* obs = (const float*)d_in[0];
    const int*   ei  = (const int*)d_in[1];
    const float* W1  = (const float*)d_in[2];
    const float* b1  = (const float*)d_in[3];
    const float* W2  = (const float*)d_in[4];
    const float* b2  = (const float*)d_in[5];
    const float* W3  = (const float*)d_in[6];
    const float* b3  = (const float*)d_in[7];
    float* out = (float*)d_out;

    char* ws = (char*)d_ws;
    size_t off = 0;
    auto alloc = [&](size_t bytes) -> void* {
        void* p = ws + off;
        off += (bytes + 255) & ~(size_t)255;
        return p;
    };
    int*   gcnt    = (int*)  alloc((size_t)NBUCK * 8 * 4);          // 18.8 KB
    int*   cursor  = (int*)  alloc((size_t)NN * 4);
    float* dinvf   = (float*)alloc((size_t)NN * 4);
    int*   csr_src = (int*)  alloc((size_t)NN * KMAX * 4);          // 19.2 MB
    int2*  ebuf    = (int2*) alloc((size_t)NBUCK * 8 * SUBCAP * 8); // 8.4 MB
    unsigned short* XB  = (unsigned short*)alloc((size_t)NN * HID * 2);
    unsigned short* XB2 = (unsigned short*)alloc((size_t)NN * HID * 2);

    const int* rowv = ei;
    const int* colv = ei + NE;

    k_zero<<<(NBUCK * 8 + 255) / 256, 256, 0, stream>>>(gcnt);
    k_part<<<PARTB, 256, 0, stream>>>(rowv, colv, gcnt, ebuf);
    k_sort_gemm1<<<NBUCK + GEMM_GRID, 256, 0, stream>>>(obs, W1, XB, gcnt, ebuf,
                                                        cursor, dinvf, csr_src);
    k_agg_gemm<<<GEMM_GRID, 256, 0, stream>>>(XB, cursor, dinvf, csr_src, b1, W2, XB2);
    k_agg_out<<<(NOUT + 15) / 16, 256, 0, stream>>>(XB2, cursor, csr_src, b2, W3, b3, out);
}

// Round 22
// 89.218 us; speedup vs baseline: 1.0828x; 1.0464x over previous
//
#include <hip/hip_runtime.h>

#define NN 150000
#define NE 600000
#define IND 128
#define HID 64
#define KMAX 32            // CSR bucket stride; in-deg ~Poisson(4), P(>32) ~ 1e-19
#define BSHIFT 8
#define NBUCK 586          // ceil(NN / 256)
#define SUBCAP 224         // per-(bucket,xcd) edge cap; mean ~129, +8 sigma
#define PARTB 293          // partition blocks, 8 edges/thread (2 x int4)
#define GEMM_GRID ((NN + 63) / 64)       // 2344
#define NOUT 120000

typedef short s16x8 __attribute__((ext_vector_type(8)));
typedef float f32x4 __attribute__((ext_vector_type(4)));

__device__ __forceinline__ unsigned f2bf(float f) {
    unsigned u = __float_as_uint(f);
    return (u + 0x7FFFu + ((u >> 16) & 1u)) >> 16;   // RNE
}

__device__ __forceinline__ unsigned cvtpk(float lo, float hi) {
    unsigned r;
    asm("v_cvt_pk_bf16_f32 %0, %1, %2" : "=v"(r) : "v"(lo), "v"(hi));
    return r;                                        // {bf16(lo), bf16(hi)} RNE
}

#define ACC4(v, dr) \
    a0 = fmaf(__uint_as_float((v).x << 16), dr, a0); \
    a1 = fmaf(__uint_as_float((v).x & 0xFFFF0000u), dr, a1); \
    a2 = fmaf(__uint_as_float((v).y << 16), dr, a2); \
    a3 = fmaf(__uint_as_float((v).y & 0xFFFF0000u), dr, a3);

// ---------------- pre: zero gcnt + build swizzled bf16 W1 image ----------------
// W1s is the byte-exact 16 KB LDS image (row*256 + ((g*16)^((row&7)<<4))), so gemm
// blocks can DMA it linearly with global_load_lds.
__global__ void k_pre(int* __restrict__ gcnt, const float* __restrict__ W1,
                      unsigned char* __restrict__ W1s) {
    int t = blockIdx.x * 256 + threadIdx.x;
    if (t < NBUCK * 8) gcnt[t] = 0;
    if (t < 1024) {                                 // 64 rows x 16 granules (16B)
        int row = t >> 4, g = t & 15;
        const float4* w4 = (const float4*)W1;
        float4 lo = w4[row * 32 + g * 2];
        float4 hi = w4[row * 32 + g * 2 + 1];
        uint4 p;
        p.x = f2bf(lo.x) | (f2bf(lo.y) << 16);
        p.y = f2bf(lo.z) | (f2bf(lo.w) << 16);
        p.z = f2bf(hi.x) | (f2bf(hi.y) << 16);
        p.w = f2bf(hi.z) | (f2bf(hi.w) << 16);
        int byte = row * 256 + ((g * 16) ^ ((row & 7) << 4));
        *(uint4*)(W1s + byte) = p;
    }
}

// ---------------- edge partition: 8 edges/thread, LDS histogram ----------------
__global__ __launch_bounds__(256) void k_part(
        const int* __restrict__ rowv, const int* __restrict__ colv,
        int* __restrict__ gcnt, int2* __restrict__ ebuf) {
    __shared__ int hist[NBUCK];
    __shared__ int bases[NBUCK];
    int tid = threadIdx.x;
    for (int i = tid; i < NBUCK; i += 256) hist[i] = 0;
    __syncthreads();
    int4 r4[2], c4[2];
    int bk[8], sl[8];
    bool val[2];
    #pragma unroll
    for (int h = 0; h < 2; ++h) {
        int t = blockIdx.x * 512 + h * 256 + tid;
        val[h] = (t < NE / 4);
        if (val[h]) {
            r4[h] = ((const int4*)rowv)[t];
            c4[h] = ((const int4*)colv)[t];
            bk[4*h+0] = c4[h].x >> BSHIFT; sl[4*h+0] = atomicAdd(&hist[bk[4*h+0]], 1);
            bk[4*h+1] = c4[h].y >> BSHIFT; sl[4*h+1] = atomicAdd(&hist[bk[4*h+1]], 1);
            bk[4*h+2] = c4[h].z >> BSHIFT; sl[4*h+2] = atomicAdd(&hist[bk[4*h+2]], 1);
            bk[4*h+3] = c4[h].w >> BSHIFT; sl[4*h+3] = atomicAdd(&hist[bk[4*h+3]], 1);
        }
    }
    __syncthreads();
    int xcd = blockIdx.x & 7;
    for (int i = tid; i < NBUCK; i += 256)
        bases[i] = hist[i] ? atomicAdd(&gcnt[i * 8 + xcd], hist[i]) : 0;
    __syncthreads();
    #pragma unroll
    for (int h = 0; h < 2; ++h) {
        if (val[h]) {
            #pragma unroll
            for (int e = 0; e < 4; ++e) {
                int c = (e == 0) ? c4[h].x : (e == 1) ? c4[h].y : (e == 2) ? c4[h].z : c4[h].w;
                int r = (e == 0) ? r4[h].x : (e == 1) ? r4[h].y : (e == 2) ? r4[h].z : r4[h].w;
                int p = bases[bk[4*h+e]] + sl[4*h+e];
                if (p < SUBCAP) ebuf[(bk[4*h+e] * 8 + xcd) * SUBCAP + p] = make_int2(c, r);
            }
        }
    }
}

// ---------------- hetero: bucket sort + gemm1 (global_load_lds staging) ----------------
// Sort blocks (first NBUCK): as before (LDS cursors; degrees + dinvf).
// gemm1 blocks: A (fp32) DMA'd via global_load_lds with PRE-SWIZZLED source
// addresses (gsrc = gdst ^ (row&7) at 16B granules) -> LDS linear write lands
// swizzled, fragment ds_read_b128 <=2-way conflicts. W1 DMA'd linearly from the
// pre-swizzled bf16 image. A fragments cvt fp32->bf16 with v_cvt_pk_bf16_f32.
// C via LDS bounce -> coalesced 16B flush.
__global__ __launch_bounds__(256) void k_sort_gemm1(
        const float* __restrict__ obs, const unsigned char* __restrict__ W1s,
        unsigned short* __restrict__ xs,
        const int* __restrict__ gcnt, const int2* __restrict__ ebuf,
        int* __restrict__ cursor, float* __restrict__ dinvf,
        int* __restrict__ csr_src) {
    __shared__ char smem[48 * 1024];            // sA fp32 32 KB + sW bf16 16 KB
    int tid = threadIdx.x;
    if (blockIdx.x < NBUCK) {
        int k = blockIdx.x;
        int lo = k << BSHIFT;
        int* cnt = (int*)smem;
        cnt[tid] = 0;
        int lens[8];
        #pragma unroll
        for (int x = 0; x < 8; ++x) {
            int l = gcnt[k * 8 + x];
            lens[x] = l > SUBCAP ? SUBCAP : l;
        }
        __syncthreads();
        for (int x = 0; x < 8; ++x) {
            const int2* run = ebuf + (size_t)(k * 8 + x) * SUBCAP;
            for (int i = tid; i < lens[x]; i += 256) {
                int2 e = run[i];
                int s = atomicAdd(&cnt[e.x - lo], 1);       // LDS atomic
                if (s < KMAX) csr_src[e.x * KMAX + s] = e.y;
            }
        }
        __syncthreads();
        int n = lo + tid;
        if (n < NN) {
            cursor[n] = cnt[tid];
            dinvf[n] = rsqrtf((float)(cnt[tid] + 1));
        }
        return;
    }
    char* sA = smem;                            // fp32 A tile, content-swizzled
    char* sW = smem + 32 * 1024;                // bf16 W tile, swizzled image
    int base = (blockIdx.x - NBUCK) * 64;

    int wave = tid >> 6, lane = tid & 63;

    // DMA W1 image: 16 chunks of 1 KB, linear
    #pragma unroll
    for (int i = 0; i < 4; ++i) {
        int c = wave * 4 + i;
        __builtin_amdgcn_global_load_lds(
            (const unsigned int*)(W1s + c * 1024 + lane * 16),
            (unsigned int*)(sW + c * 1024), 16, 0, 0);
    }
    // DMA A tile: 32 chunks of 1 KB (2 rows each); source pre-swizzled per lane
    #pragma unroll
    for (int i = 0; i < 8; ++i) {
        int c = wave * 8 + i;
        int rowl = 2 * c + (lane >> 5);
        int n = base + rowl; if (n >= NN) n = NN - 1;    // clamp; C-write guarded
        int gsrc = (lane & 31) ^ (rowl & 7);
        __builtin_amdgcn_global_load_lds(
            (const unsigned int*)((const char*)obs + (size_t)n * 512 + gsrc * 16),
            (unsigned int*)(sA + c * 1024), 16, 0, 0);
    }
    __syncthreads();                            // drains vmcnt (incl. load_lds)

    int wr = wave >> 1, wc = wave & 1;
    int r16 = lane & 15, kg = lane >> 4;

    f32x4 acc[2][2];
    #pragma unroll
    for (int i = 0; i < 2; ++i)
        #pragma unroll
        for (int j = 0; j < 2; ++j)
            acc[i][j] = (f32x4){0.f, 0.f, 0.f, 0.f};

    #pragma unroll
    for (int s = 0; s < IND / 32; ++s) {
        s16x8 a[2], b[2];
        #pragma unroll
        for (int i = 0; i < 2; ++i) {
            int row = 32 * wr + 16 * i + r16;
            int g = s * 8 + kg * 2;             // even granule pair
            int sw = row & 7;
            float4 lo4 = *(const float4*)(sA + row * 512 + ((g ^ sw) << 4));
            float4 hi4 = *(const float4*)(sA + row * 512 + (((g + 1) ^ sw) << 4));
            uint4 av;
            av.x = cvtpk(lo4.x, lo4.y);
            av.y = cvtpk(lo4.z, lo4.w);
            av.z = cvtpk(hi4.x, hi4.y);
            av.w = cvtpk(hi4.z, hi4.w);
            a[i] = __builtin_bit_cast(s16x8, av);
        }
        int kb = (s * 32 + kg * 8) * 2;
        #pragma unroll
        for (int j = 0; j < 2; ++j) {
            int row = 32 * wc + 16 * j + r16;
            int byte = row * (IND * 2) + kb;
            byte ^= (row & 7) << 4;
            b[j] = *(const s16x8*)(sW + byte);
        }
        #pragma unroll
        for (int i = 0; i < 2; ++i)
            #pragma unroll
            for (int j = 0; j < 2; ++j)
                acc[i][j] = __builtin_amdgcn_mfma_f32_16x16x32_bf16(a[i], b[j], acc[i][j], 0, 0, 0);
    }

    // C via LDS bounce (sA dead) -> coalesced 16B flush
    __syncthreads();
    unsigned short* sC = (unsigned short*)sA;
    #pragma unroll
    for (int i = 0; i < 2; ++i) {
        #pragma unroll
        for (int r = 0; r < 4; ++r) {
            int nloc = 32 * wr + 16 * i + kg * 4 + r;
            #pragma unroll
            for (int j = 0; j < 2; ++j) {
                int c = 32 * wc + 16 * j + r16;
                sC[nloc * 64 + c] = (unsigned short)f2bf(acc[i][j][r]);
            }
        }
    }
    __syncthreads();
    {
        uint4* dst = (uint4*)(xs + (size_t)base * HID);
        const uint4* s4p = (const uint4*)sC;
        #pragma unroll
        for (int k2 = 0; k2 < 2; ++k2) {
            int idx = k2 * 256 + tid;           // 8 uint4 per node row
            if (base + (idx >> 3) < NN) dst[idx] = s4p[idx];
        }
    }
}

// ---------------- fused agg1 + gemm2 (branch-free gathers; C via LDS flush) ----------------
__global__ __launch_bounds__(256) void k_agg_gemm(
        const unsigned short* __restrict__ xs, const int* __restrict__ cursor,
        const float* __restrict__ dinvf, const int* __restrict__ csr_src,
        const float* __restrict__ bias, const float* __restrict__ W2,
        unsigned short* __restrict__ xs2) {
    __shared__ char smem[2 * 64 * HID * 2];
    char* sA = smem;
    char* sB = smem + 64 * HID * 2;
    int tid = threadIdx.x;
    int base = blockIdx.x * 64;

    {   // stage W2 fp32 -> bf16 swizzled (64 rows x 16 float4)
        const float4* Wsrc = (const float4*)W2;
        for (int idx = tid; idx < 64 * 16; idx += 256) {
            int row = idx >> 4, c4i = idx & 15;
            float4 w = Wsrc[idx];
            uint2 p;
            p.x = f2bf(w.x) | (f2bf(w.y) << 16);
            p.y = f2bf(w.z) | (f2bf(w.w) << 16);
            int byte = row * (HID * 2) + c4i * 8;
            byte ^= (row & 7) << 4;
            *(uint2*)(sB + byte) = p;
        }
    }

    int lane = tid & 63;
    int l16 = lane & 15, gbase = lane & 48;
    int grp = tid >> 4;
    const uint2* src = (const uint2*)xs;
    float4 bb = ((const float4*)bias)[l16];

    int degA[4], cntA[4], idxA[4];
    uint2 svA[4];
    float drA[4];
    #pragma unroll
    for (int s4 = 0; s4 < 4; ++s4) {
        int node = base + s4 * 16 + grp;
        bool ok = node < NN;
        int nc = ok ? node : NN - 1;
        int deg = cursor[nc];
        degA[s4] = deg;
        cntA[s4] = ok ? (deg < KMAX ? deg : KMAX) : 0;
        idxA[s4] = csr_src[nc * KMAX + l16];    // 64B/group: slots 0..15
        svA[s4]  = src[(size_t)nc * 16 + l16];  // self row
    }
    #pragma unroll
    for (int s4 = 0; s4 < 4; ++s4) {
        drA[s4] = (l16 < cntA[s4]) ? dinvf[idxA[s4]] : 0.0f;
    }

    #pragma unroll
    for (int s4 = 0; s4 < 4; ++s4) {
        int row = s4 * 16 + grp;
        int node = base + row;
        int cnt = cntA[s4];
        float dn = rsqrtf((float)(degA[s4] + 1));
        uint2 sv = svA[s4];
        float a0 = __uint_as_float(sv.x << 16) * dn;
        float a1 = __uint_as_float(sv.x & 0xFFFF0000u) * dn;
        float a2 = __uint_as_float(sv.y << 16) * dn;
        float a3 = __uint_as_float(sv.y & 0xFFFF0000u) * dn;
        uint2 v[8];
        #pragma unroll
        for (int j = 0; j < 8; ++j) {
            int r = __shfl(idxA[s4], gbase + j, 64);
            r = (j < cnt) ? r : 0;
            v[j] = src[(size_t)r * 16 + l16];
        }
        #pragma unroll
        for (int j = 0; j < 8; ++j) {
            float dr = __shfl(drA[s4], gbase + j, 64);  // 0 for invalid slots
            ACC4(v[j], dr)
        }
        if (cnt > 8) {
            int c16 = cnt < 16 ? cnt : 16;
            for (int j = 8; j < c16; ++j) {
                int r    = __shfl(idxA[s4], gbase + j, 64);
                float dr = __shfl(drA[s4], gbase + j, 64);
                uint2 vv = src[(size_t)r * 16 + l16];
                ACC4(vv, dr)
            }
            for (int j = 16; j < cnt; ++j) {    // ultra-rare
                int r = csr_src[node * KMAX + j];
                float dr = dinvf[r];
                uint2 vv = src[(size_t)r * 16 + l16];
                ACC4(vv, dr)
            }
        }
        float h0 = fmaxf(fmaf(dn, a0, bb.x), 0.f);
        float h1 = fmaxf(fmaf(dn, a1, bb.y), 0.f);
        float h2 = fmaxf(fmaf(dn, a2, bb.z), 0.f);
        float h3 = fmaxf(fmaf(dn, a3, bb.w), 0.f);
        uint2 o;
        o.x = f2bf(h0) | (f2bf(h1) << 16);
        o.y = f2bf(h2) | (f2bf(h3) << 16);
        if (node >= NN) { o.x = 0u; o.y = 0u; }
        int byte = row * (HID * 2) + l16 * 8;
        byte ^= (row & 7) << 4;
        *(uint2*)(sA + byte) = o;
    }
    __syncthreads();

    int wave = tid >> 6;
    int wr = wave >> 1, wc = wave & 1;
    int r16 = lane & 15, kg = lane >> 4;

    f32x4 acc[2][2];
    #pragma unroll
    for (int i = 0; i < 2; ++i)
        #pragma unroll
        for (int j = 0; j < 2; ++j)
            acc[i][j] = (f32x4){0.f, 0.f, 0.f, 0.f};

    #pragma unroll
    for (int s = 0; s < HID / 32; ++s) {
        int kb = (s * 32 + kg * 8) * 2;
        s16x8 a[2], bfr[2];
        #pragma unroll
        for (int i = 0; i < 2; ++i) {
            int row = 32 * wr + 16 * i + r16;
            int byte = row * (HID * 2) + kb;
            byte ^= (row & 7) << 4;
            a[i] = *(const s16x8*)(sA + byte);
        }
        #pragma unroll
        for (int j = 0; j < 2; ++j) {
            int row = 32 * wc + 16 * j + r16;
            int byte = row * (HID * 2) + kb;
            byte ^= (row & 7) << 4;
            bfr[j] = *(const s16x8*)(sB + byte);
        }
        #pragma unroll
        for (int i = 0; i < 2; ++i)
            #pragma unroll
            for (int j = 0; j < 2; ++j)
                acc[i][j] = __builtin_amdgcn_mfma_f32_16x16x32_bf16(a[i], bfr[j], acc[i][j], 0, 0, 0);
    }

    // C via LDS bounce (sA dead) -> coalesced flush, pre-scaled by dinvf[n]
    __syncthreads();
    unsigned short* sC = (unsigned short*)sA;
    #pragma unroll
    for (int i = 0; i < 2; ++i) {
        #pragma unroll
        for (int r = 0; r < 4; ++r) {
            int nloc = 32 * wr + 16 * i + kg * 4 + r;
            int n = base + nloc;
            float d = dinvf[n < NN ? n : NN - 1];
            #pragma unroll
            for (int j = 0; j < 2; ++j) {
                int c = 32 * wc + 16 * j + r16;
                sC[nloc * 64 + c] = (unsigned short)f2bf(acc[i][j][r] * d);
            }
        }
    }
    __syncthreads();
    {
        uint4* dst = (uint4*)(xs2 + (size_t)base * HID);
        const uint4* s4p = (const uint4*)sC;
        #pragma unroll
        for (int k2 = 0; k2 < 2; ++k2) {
            int idx = k2 * 256 + tid;
            if (base + (idx >> 3) < NN) dst[idx] = s4p[idx];
        }
    }
}

// ---------------- agg2 + final dot (needed nodes only; batched gathers) ----------------
__global__ __launch_bounds__(256) void k_agg_out(const unsigned short* __restrict__ xs,
                      const int* __restrict__ cursor, const int* __restrict__ csr_src,
                      const float* __restrict__ bias, const float* __restrict__ W3,
                      const float* __restrict__ b3, float* __restrict__ outp) {
    int tid = threadIdx.x;
    int lane = tid & 63;
    int l16 = lane & 15, gbase = lane & 48;
    int q = blockIdx.x * 16 + (tid >> 4);
    if (q >= NOUT) return;
    int g15 = q / 12, jj12 = q - g15 * 12;
    int node = g15 * 15 + 3 + jj12;
    int deg = cursor[node];
    int cnt = deg < KMAX ? deg : KMAX;
    float dn = rsqrtf((float)(deg + 1));
    const uint2* src = (const uint2*)xs;
    int idx0 = csr_src[node * KMAX + l16];      // 64B: slots 0..15
    float w0 = (l16 < cnt) ? 1.0f : 0.0f;       // slot validity weight
    uint2 sv = src[(size_t)node * 16 + l16];
    float a0 = __uint_as_float(sv.x << 16);
    float a1 = __uint_as_float(sv.x & 0xFFFF0000u);
    float a2 = __uint_as_float(sv.y << 16);
    float a3 = __uint_as_float(sv.y & 0xFFFF0000u);
    uint2 v[8];
    #pragma unroll
    for (int j = 0; j < 8; ++j) {
        int r = __shfl(idx0, gbase + j, 64);
        r = (j < cnt) ? r : 0;
        v[j] = src[(size_t)r * 16 + l16];
    }
    #pragma unroll
    for (int j = 0; j < 8; ++j) {
        float w = __shfl(w0, gbase + j, 64);
        ACC4(v[j], w)
    }
    if (cnt > 8) {
        int c16 = cnt < 16 ? cnt : 16;
        for (int j = 8; j < c16; ++j) {
            int r = __shfl(idx0, gbase + j, 64);
            uint2 vv = src[(size_t)r * 16 + l16];
            ACC4(vv, 1.0f)
        }
        for (int j = 16; j < cnt; ++j) {
            int r = csr_src[node * KMAX + j];
            uint2 vv = src[(size_t)r * 16 + l16];
            ACC4(vv, 1.0f)
        }
    }
    float4 bb = ((const float4*)bias)[l16];
    float h0 = fmaxf(fmaf(dn, a0, bb.x), 0.f);
    float h1 = fmaxf(fmaf(dn, a1, bb.y), 0.f);
    float h2 = fmaxf(fmaf(dn, a2, bb.z), 0.f);
    float h3 = fmaxf(fmaf(dn, a3, bb.w), 0.f);
    float4 ww = ((const float4*)W3)[l16];
    float v3 = h0 * ww.x + h1 * ww.y + h2 * ww.z + h3 * ww.w;
    v3 += __shfl_xor(v3, 1, 64);
    v3 += __shfl_xor(v3, 2, 64);
    v3 += __shfl_xor(v3, 4, 64);
    v3 += __shfl_xor(v3, 8, 64);                // reduce within the 16-lane group
    if (l16 == 0) outp[q] = v3 + b3[0];
}

extern "C" void kernel_launch(void* const* d_in, const int* in_sizes, int n_in,
                              void* d_out, int out_size, void* d_ws, size_t ws_size,
                              hipStream_t stream) {
    const float* obs = (const float*)d_in[0];
    const int*   ei  = (const int*)d_in[1];
    const float* W1  = (const float*)d_in[2];
    const float* b1  = (const float*)d_in[3];
    const float* W2  = (const float*)d_in[4];
    const float* b2  = (const float*)d_in[5];
    const float* W3  = (const float*)d_in[6];
    const float* b3  = (const float*)d_in[7];
    float* out = (float*)d_out;

    char* ws = (char*)d_ws;
    size_t off = 0;
    auto alloc = [&](size_t bytes) -> void* {
        void* p = ws + off;
        off += (bytes + 255) & ~(size_t)255;
        return p;
    };
    int*   gcnt    = (int*)  alloc((size_t)NBUCK * 8 * 4);          // 18.8 KB
    int*   cursor  = (int*)  alloc((size_t)NN * 4);
    float* dinvf   = (float*)alloc((size_t)NN * 4);
    int*   csr_src = (int*)  alloc((size_t)NN * KMAX * 4);          // 19.2 MB
    int2*  ebuf    = (int2*) alloc((size_t)NBUCK * 8 * SUBCAP * 8); // 8.4 MB
    unsigned char* W1s = (unsigned char*)alloc(16 * 1024);          // swizzled bf16 W1
    unsigned short* XB  = (unsigned short*)alloc((size_t)NN * HID * 2);
    unsigned short* XB2 = (unsigned short*)alloc((size_t)NN * HID * 2);

    const int* rowv = ei;
    const int* colv = ei + NE;

    k_pre <<<(NBUCK * 8 + 255) / 256, 256, 0, stream>>>(gcnt, W1, W1s);
    k_part<<<PARTB, 256, 0, stream>>>(rowv, colv, gcnt, ebuf);
    k_sort_gemm1<<<NBUCK + GEMM_GRID, 256, 0, stream>>>(obs, W1s, XB, gcnt, ebuf,
                                                        cursor, dinvf, csr_src);
    k_agg_gemm<<<GEMM_GRID, 256, 0, stream>>>(XB, cursor, dinvf, csr_src, b1, W2, XB2);
    k_agg_out<<<(NOUT + 15) / 16, 256, 0, stream>>>(XB2, cursor, csr_src, b2, W3, b3, out);
}